// Round 7
// baseline (591.870 us; speedup 1.0000x reference)
//
#include <hip/hip_runtime.h>
#include <math.h>

typedef __attribute__((ext_vector_type(4))) float f32x4;
typedef __attribute__((ext_vector_type(8))) short bf16x8;
typedef __attribute__((ext_vector_type(4))) short s16x4;

#if __has_builtin(__builtin_amdgcn_exp2f)
#define EXP2(x) __builtin_amdgcn_exp2f(x)
#else
#define EXP2(x) exp2f(x)
#endif

__device__ __forceinline__ unsigned short f2bf(float f) {
  union { float f; unsigned u; } v; v.f = f;
  return (unsigned short)((v.u + 0x7fffu + ((v.u >> 16) & 1u)) >> 16);
}

// ---------------- LayerNorm: one block per row of 512, bf16 output ----------------
__global__ void ln_kernel(const float* __restrict__ in, const float* __restrict__ w,
                          const float* __restrict__ b, unsigned short* __restrict__ out) {
  __shared__ float sh[4];
  const int t = threadIdx.x;
  const float* p = in + (size_t)blockIdx.x * 512;
  float a0 = p[t], a1 = p[t + 256];
  float s = a0 + a1;
#pragma unroll
  for (int o = 32; o; o >>= 1) s += __shfl_down(s, o);
  if ((t & 63) == 0) sh[t >> 6] = s;
  __syncthreads();
  s = sh[0] + sh[1] + sh[2] + sh[3];
  float mu = s * (1.0f / 512.0f);
  float d0 = a0 - mu, d1 = a1 - mu;
  float q = d0 * d0 + d1 * d1;
  __syncthreads();
#pragma unroll
  for (int o = 32; o; o >>= 1) q += __shfl_down(q, o);
  if ((t & 63) == 0) sh[t >> 6] = q;
  __syncthreads();
  q = sh[0] + sh[1] + sh[2] + sh[3];
  float rstd = rsqrtf(q * (1.0f / 512.0f) + 1e-5f);
  unsigned short* po = out + (size_t)blockIdx.x * 512;
  po[t]       = f2bf(d0 * rstd * w[t] + b[t]);
  po[t + 256] = f2bf(d1 * rstd * w[t + 256] + b[t + 256]);
}

// ---- ALL weight transposes in one launch: fp32 (K x N) -> bf16 (N x K) ----
__global__ void transpose_all(const float* __restrict__ w0, unsigned short* __restrict__ o0,
                              const float* __restrict__ w1, unsigned short* __restrict__ o1,
                              const float* __restrict__ w2, unsigned short* __restrict__ o2,
                              const float* __restrict__ w3, unsigned short* __restrict__ o3) {
  __shared__ float tile[32][33];
  int idx = blockIdx.x;
  const float* in; unsigned short* out; int ldi, ldo, nx;
  if (idx < 768)        { in = w0; out = o0; ldi = 1536; ldo = 512;  nx = 48; }
  else if (idx < 1024)  { idx -= 768;  in = w1; out = o1; ldi = 512;  ldo = 512;  nx = 16; }
  else if (idx < 3072)  { idx -= 1024; in = w2; out = o2; ldi = 4096; ldo = 512;  nx = 128; }
  else                  { idx -= 3072; in = w3; out = o3; ldi = 512;  ldo = 2048; nx = 16; }
  const int tx = threadIdx.x & 31;
  const int ty = threadIdx.x >> 5;  // 0..7
  const int n0 = (idx % nx) * 32, k0 = (idx / nx) * 32;
#pragma unroll
  for (int i = 0; i < 4; ++i)
    tile[ty + i * 8][tx] = in[(size_t)(k0 + ty + i * 8) * ldi + n0 + tx];
  __syncthreads();
#pragma unroll
  for (int i = 0; i < 4; ++i)
    out[(size_t)(n0 + ty + i * 8) * ldo + k0 + tx] = f2bf(tile[tx][ty + i * 8]);
}

// ---------------- bf16 x bf16 MFMA GEMM, BK=64, padded LDS ----------------
// EPI: 0 = +bias (fp32); 3 = resid + (acc+bias)*gamma (fp32);
//      4 = QKV: cols<1024 -> bf16 qkvbf (cols<512 pre-scaled by 0.125*log2e),
//               cols in [1024,1536) -> bf16 transposed into vt[bh][d][l]
template <int WM, int WN, int TM, int TN, int EPI>
__global__ __launch_bounds__(256) void gemm_bb(
    const unsigned short* __restrict__ A, const unsigned short* __restrict__ Bt,
    float* __restrict__ C, unsigned short* __restrict__ Cbf, unsigned short* __restrict__ Vt,
    int K, int lda, int ldb, int ldc,
    const float* __restrict__ bias, const float* __restrict__ resid,
    const float* __restrict__ gamma) {
  constexpr int BM = WM * TM * 16;
  constexpr int BN = WN * TN * 16;
  constexpr int LDS_STRIDE = 72;   // 64 + 8 pad: breaks 8-way bank conflicts
  __shared__ short As[BM * LDS_STRIDE];
  __shared__ short Bs[BN * LDS_STRIDE];

  const int tid = threadIdx.x;
  const int m0 = blockIdx.y * BM, n0 = blockIdx.x * BN;
  const int w = tid >> 6, lane = tid & 63;
  const int wm = w / WN, wn = w % WN;
  const int lrow = lane & 15, lq = lane >> 4;

  f32x4 acc[TM][TN];
#pragma unroll
  for (int i = 0; i < TM; ++i)
#pragma unroll
    for (int j = 0; j < TN; ++j) acc[i][j] = (f32x4){0.f, 0.f, 0.f, 0.f};

  for (int k0 = 0; k0 < K; k0 += 64) {
    __syncthreads();
#pragma unroll
    for (int it = 0; it < BM / 32; ++it) {
      int c = it * 256 + tid;
      int row = c >> 3, col = (c & 7) << 3;
      *(bf16x8*)(As + row * LDS_STRIDE + col) =
          *(const bf16x8*)(A + (size_t)(m0 + row) * lda + k0 + col);
    }
#pragma unroll
    for (int it = 0; it < BN / 32; ++it) {
      int c = it * 256 + tid;
      int row = c >> 3, col = (c & 7) << 3;
      *(bf16x8*)(Bs + row * LDS_STRIDE + col) =
          *(const bf16x8*)(Bt + (size_t)(n0 + row) * ldb + k0 + col);
    }
    __syncthreads();

    bf16x8 af[TM][2], bf[TN][2];
#pragma unroll
    for (int mi = 0; mi < TM; ++mi)
#pragma unroll
      for (int c = 0; c < 2; ++c)
        af[mi][c] = *(const bf16x8*)(As + (wm * TM * 16 + mi * 16 + lrow) * LDS_STRIDE + c * 32 + lq * 8);
#pragma unroll
    for (int nj = 0; nj < TN; ++nj)
#pragma unroll
      for (int c = 0; c < 2; ++c)
        bf[nj][c] = *(const bf16x8*)(Bs + (wn * TN * 16 + nj * 16 + lrow) * LDS_STRIDE + c * 32 + lq * 8);
#pragma unroll
    for (int mi = 0; mi < TM; ++mi)
#pragma unroll
      for (int nj = 0; nj < TN; ++nj)
#pragma unroll
        for (int c = 0; c < 2; ++c)
          acc[mi][nj] = __builtin_amdgcn_mfma_f32_16x16x32_bf16(af[mi][c], bf[nj][c], acc[mi][nj], 0, 0, 0);
  }

#pragma unroll
  for (int mi = 0; mi < TM; ++mi) {
#pragma unroll
    for (int nj = 0; nj < TN; ++nj) {
      int gm0 = m0 + wm * TM * 16 + mi * 16 + lq * 4;
      int gn = n0 + wn * TN * 16 + nj * 16 + lrow;
      if constexpr (EPI == 4) {
        if (gn >= 1024) {
          // V columns -> vt[bh][d][l] transposed bf16 (4 consecutive l per thread)
          int h = (gn - 1024) >> 6, dd = (gn - 1024) & 63;
          int bb = gm0 >> 11, l0 = gm0 & 2047;
          float bs = bias[gn];
          s16x4 r4 = {(short)f2bf(acc[mi][nj][0] + bs), (short)f2bf(acc[mi][nj][1] + bs),
                      (short)f2bf(acc[mi][nj][2] + bs), (short)f2bf(acc[mi][nj][3] + bs)};
          *(s16x4*)(Vt + ((size_t)(bb * 8 + h) * 64 + dd) * 2048 + l0) = r4;
          continue;
        }
      }
#pragma unroll
      for (int r = 0; r < 4; ++r) {
        int gm = gm0 + r;
        size_t idx = (size_t)gm * ldc + gn;
        float v = acc[mi][nj][r];
        if constexpr (EPI == 0) {
          C[idx] = v + bias[gn];
        } else if constexpr (EPI == 4) {
          float u = v + bias[gn];
          Cbf[idx] = f2bf(gn < 512 ? u * 0.18033688011112042f : u);
        } else {
          C[idx] = resid[idx] + (v + bias[gn]) * gamma[gn];
        }
      }
    }
  }
}

// --------- FFN1 + GELU gate fused, BK=64, padded LDS, bf16 out ---------
__global__ __launch_bounds__(256) void ffn1_gate_kernel(
    const unsigned short* __restrict__ A, const unsigned short* __restrict__ Bt,
    unsigned short* __restrict__ F, const float* __restrict__ bias) {
  constexpr int LDS_STRIDE = 72;
  __shared__ short As[128 * LDS_STRIDE];
  __shared__ short Bs[64 * LDS_STRIDE];
  __shared__ short Bs2[64 * LDS_STRIDE];

  const int tid = threadIdx.x;
  const int n0 = blockIdx.x * 64, m0 = blockIdx.y * 128;
  const int w = tid >> 6, lane = tid & 63;
  const int wm = w >> 1, wn = w & 1;
  const int lrow = lane & 15, lq = lane >> 4;

  f32x4 acca[4][2], accb[4][2];
#pragma unroll
  for (int i = 0; i < 4; ++i)
#pragma unroll
    for (int j = 0; j < 2; ++j) {
      acca[i][j] = (f32x4){0.f, 0.f, 0.f, 0.f};
      accb[i][j] = (f32x4){0.f, 0.f, 0.f, 0.f};
    }

  for (int k0 = 0; k0 < 512; k0 += 64) {
    __syncthreads();
#pragma unroll
    for (int it = 0; it < 4; ++it) {
      int c = it * 256 + tid;
      int row = c >> 3, col = (c & 7) << 3;
      *(bf16x8*)(As + row * LDS_STRIDE + col) =
          *(const bf16x8*)(A + (size_t)(m0 + row) * 512 + k0 + col);
    }
#pragma unroll
    for (int it = 0; it < 2; ++it) {
      int c = it * 256 + tid;
      int row = c >> 3, col = (c & 7) << 3;
      *(bf16x8*)(Bs + row * LDS_STRIDE + col) =
          *(const bf16x8*)(Bt + (size_t)(n0 + row) * 512 + k0 + col);
      *(bf16x8*)(Bs2 + row * LDS_STRIDE + col) =
          *(const bf16x8*)(Bt + (size_t)(2048 + n0 + row) * 512 + k0 + col);
    }
    __syncthreads();

    bf16x8 af[4][2], ba[2][2], bb[2][2];
#pragma unroll
    for (int mi = 0; mi < 4; ++mi)
#pragma unroll
      for (int c = 0; c < 2; ++c)
        af[mi][c] = *(const bf16x8*)(As + (wm * 64 + mi * 16 + lrow) * LDS_STRIDE + c * 32 + lq * 8);
#pragma unroll
    for (int nj = 0; nj < 2; ++nj)
#pragma unroll
      for (int c = 0; c < 2; ++c) {
        ba[nj][c] = *(const bf16x8*)(Bs + (wn * 32 + nj * 16 + lrow) * LDS_STRIDE + c * 32 + lq * 8);
        bb[nj][c] = *(const bf16x8*)(Bs2 + (wn * 32 + nj * 16 + lrow) * LDS_STRIDE + c * 32 + lq * 8);
      }
#pragma unroll
    for (int mi = 0; mi < 4; ++mi)
#pragma unroll
      for (int nj = 0; nj < 2; ++nj)
#pragma unroll
        for (int c = 0; c < 2; ++c) {
          acca[mi][nj] = __builtin_amdgcn_mfma_f32_16x16x32_bf16(af[mi][c], ba[nj][c], acca[mi][nj], 0, 0, 0);
          accb[mi][nj] = __builtin_amdgcn_mfma_f32_16x16x32_bf16(af[mi][c], bb[nj][c], accb[mi][nj], 0, 0, 0);
        }
  }

#pragma unroll
  for (int mi = 0; mi < 4; ++mi)
#pragma unroll
    for (int nj = 0; nj < 2; ++nj) {
      int gm0 = m0 + wm * 64 + mi * 16 + lq * 4;
      int gn = n0 + wn * 32 + nj * 16 + lrow;
#pragma unroll
      for (int r = 0; r < 4; ++r) {
        float a = acca[mi][nj][r] + bias[gn];
        float bg = accb[mi][nj][r] + bias[2048 + gn];
        float g = 0.5f * bg * (1.0f + erff(bg * 0.70710678118654752f));
        F[(size_t)(gm0 + r) * 2048 + gn] = f2bf(g * a);
      }
    }
}

// --------- Fused attention v5: R5 geometry + explicit cross-tile K prefetch ---------
// Block: 32 q-rows x one (b,h). 4 waves (2 wm x 2 wn). K fragments double-buffered
// in registers (ping-pong), issued one full tile body ahead -> hides L2 latency.
__global__ __launch_bounds__(256, 4) void attn_fused(
    const unsigned short* __restrict__ qkvbf, const unsigned short* __restrict__ vt,
    const float* __restrict__ rel, float* __restrict__ attn, unsigned short* __restrict__ o) {
  __shared__ __align__(16) float p_f32[4 * 16 * 64];  // 16 KB wave-private staging; reused as O scratch
  __shared__ float erel[256];
  __shared__ float rsum[32];
  __shared__ float rinv[32];

  const int tid = threadIdx.x;
  const int flat = blockIdx.y * 64 + blockIdx.x;   // 1024 blocks
  const int swz = (flat & 7) * 128 + (flat >> 3);  // XCD-contiguous
  const int bh = swz >> 6;
  const int m0 = (swz & 63) * 32;
  const int b = bh >> 3, h = bh & 7;

  const int w = tid >> 6, lane = tid & 63;
  const int wm = w >> 1, wn = w & 1;
  const int lrow = lane & 15, lq = lane >> 4;

  const unsigned short* qb = qkvbf + (size_t)(b * 2048) * 1536 + h * 64;
  const unsigned short* kb = qb + 512;
  const unsigned short* vb = vt + (size_t)bh * 64 * 2048;
  float* ab = attn + (size_t)bh * 2048 * 2048;
  const float* relh = rel + h * 255;

  if (tid < 32) rsum[tid] = 0.f;
  if (tid < 255) erel[tid] = __expf(relh[tid]);

  bf16x8 qf[2];
#pragma unroll
  for (int c = 0; c < 2; ++c)
    qf[c] = *(const bf16x8*)(qb + (size_t)(m0 + wm * 16 + lrow) * 1536 + c * 32 + lq * 8);

  const unsigned short* krow = kb + (size_t)(wn * 64 + lrow) * 1536 + lq * 8;
  const unsigned short* vrow = vb + (size_t)lrow * 2048 + wn * 64 + lq * 8;

  __syncthreads();  // erel + rsum ready

  // K fragment loader: 8 x 16B per tile per wave
  auto LDK = [&](int t, bf16x8 (&kf)[2][4]) {
#pragma unroll
    for (int c = 0; c < 2; ++c)
#pragma unroll
      for (int nj = 0; nj < 4; ++nj)
        kf[c][nj] = *(const bf16x8*)(krow + (size_t)(t * 128 + nj * 16) * 1536 + c * 32);
  };

  // ---- pass 1: row sums of exp(s) ----
  float psum[4] = {0.f, 0.f, 0.f, 0.f};
  const int dbase = (m0 + wm * 16 + lq * 4) - (wn * 64 + lrow);

  auto P1 = [&](int t, bf16x8 (&kf)[2][4]) {
    const int kt0 = t * 128;
    f32x4 acc[4];
#pragma unroll
    for (int nj = 0; nj < 4; ++nj) acc[nj] = (f32x4){0.f, 0.f, 0.f, 0.f};
#pragma unroll
    for (int c = 0; c < 2; ++c)
#pragma unroll
      for (int nj = 0; nj < 4; ++nj)
        acc[nj] = __builtin_amdgcn_mfma_f32_16x16x32_bf16(qf[c], kf[c][nj], acc[nj], 0, 0, 0);
    const int Dt = m0 - kt0;
    if (Dt >= 256 || Dt <= -160) {      // fully clamped tile: uniform rel bias
      float ec = erel[Dt >= 256 ? 254 : 0];
#pragma unroll
      for (int r = 0; r < 4; ++r) {
        float s = 0.f;
#pragma unroll
        for (int nj = 0; nj < 4; ++nj) s += EXP2(acc[nj][r]);
        psum[r] += ec * s;
      }
    } else {
#pragma unroll
      for (int nj = 0; nj < 4; ++nj) {
        int d0 = dbase - kt0 - nj * 16;
#pragma unroll
        for (int r = 0; r < 4; ++r) {
          int d = d0 + r;
          d = d < -127 ? -127 : (d > 127 ? 127 : d);
          psum[r] += EXP2(acc[nj][r]) * erel[d + 127];
        }
      }
    }
  };

  {
    bf16x8 kA[2][4], kB[2][4];
    LDK(0, kA);
#pragma unroll 1
    for (int tt = 0; tt < 8; ++tt) {
      LDK(2 * tt + 1, kB);
      P1(2 * tt, kA);
      if (tt < 7) LDK(2 * tt + 2, kA);
      P1(2 * tt + 1, kB);
    }
  }

#pragma unroll
  for (int off = 1; off < 16; off <<= 1)
#pragma unroll
    for (int r = 0; r < 4; ++r) psum[r] += __shfl_xor(psum[r], off);
  if (lrow == 0) {
#pragma unroll
    for (int r = 0; r < 4; ++r) atomicAdd(&rsum[wm * 16 + lq * 4 + r], psum[r]);
  }
  __syncthreads();
  if (tid < 32) rinv[tid] = 1.0f / rsum[tid];
  __syncthreads();
  float rv[4];
#pragma unroll
  for (int r = 0; r < 4; ++r) rv[r] = rinv[wm * 16 + lq * 4 + r];

  // ---- pass 2: recompute S, stage in LDS, coalesced attn store, O += P @ V ----
  f32x4 oacc[4];
#pragma unroll
  for (int nj = 0; nj < 4; ++nj) oacc[nj] = (f32x4){0.f, 0.f, 0.f, 0.f};
  float* pw = p_f32 + w * (16 * 64);   // wave-private 4 KB
  const int wsw = lq << 4;
  const int rsw = ((lrow >> 2) & 3) << 4;

  auto P2 = [&](int t, bf16x8 (&kf)[2][4]) {
    const int kt0 = t * 128;
    f32x4 acc[4];
#pragma unroll
    for (int nj = 0; nj < 4; ++nj) acc[nj] = (f32x4){0.f, 0.f, 0.f, 0.f};
#pragma unroll
    for (int c = 0; c < 2; ++c)
#pragma unroll
      for (int nj = 0; nj < 4; ++nj)
        acc[nj] = __builtin_amdgcn_mfma_f32_16x16x32_bf16(qf[c], kf[c][nj], acc[nj], 0, 0, 0);

    const int Dt = m0 - kt0;
    if (Dt >= 256 || Dt <= -160) {
      float ec = erel[Dt >= 256 ? 254 : 0];
#pragma unroll
      for (int r = 0; r < 4; ++r) {
        float fr = ec * rv[r];
        int prow = lq * 4 + r;
#pragma unroll
        for (int nj = 0; nj < 4; ++nj)
          pw[prow * 64 + ((nj * 16 + lrow) ^ wsw)] = EXP2(acc[nj][r]) * fr;
      }
    } else {
#pragma unroll
      for (int r = 0; r < 4; ++r) {
        int prow = lq * 4 + r;
        int d0 = dbase - kt0 + r;
#pragma unroll
        for (int nj = 0; nj < 4; ++nj) {
          int d = d0 - nj * 16;
          d = d < -127 ? -127 : (d > 127 ? 127 : d);
          pw[prow * 64 + ((nj * 16 + lrow) ^ wsw)] = EXP2(acc[nj][r]) * (erel[d + 127] * rv[r]);
        }
      }
    }

    // coalesced attn store: 4 x f32x4, each quarter-wave covers a 256B row run
#pragma unroll
    for (int it = 0; it < 4; ++it) {
      int rr = lq * 4 + it;
      f32x4 vv = *(const f32x4*)(pw + rr * 64 + ((lrow * 4) ^ wsw));
      __builtin_nontemporal_store(
          vv, (f32x4*)(ab + (size_t)(m0 + wm * 16 + rr) * 2048 + kt0 + wn * 64 + lrow * 4));
    }

    // PV over this wave's 64 keys (same-wave LDS read, lgkmcnt only)
#pragma unroll
    for (int c2 = 0; c2 < 2; ++c2) {
      const float* pp = pw + lrow * 64 + ((c2 * 32 + lq * 8) ^ rsw);
      f32x4 pa = *(const f32x4*)pp;
      f32x4 pb = *(const f32x4*)(pp + 4);
      bf16x8 ap = {(short)f2bf(pa[0]), (short)f2bf(pa[1]), (short)f2bf(pa[2]), (short)f2bf(pa[3]),
                   (short)f2bf(pb[0]), (short)f2bf(pb[1]), (short)f2bf(pb[2]), (short)f2bf(pb[3])};
      bf16x8 bv[4];
#pragma unroll
      for (int nj = 0; nj < 4; ++nj)
        bv[nj] = *(const bf16x8*)(vrow + (size_t)(nj * 16) * 2048 + kt0 + c2 * 32);
#pragma unroll
      for (int nj = 0; nj < 4; ++nj)
        oacc[nj] = __builtin_amdgcn_mfma_f32_16x16x32_bf16(ap, bv[nj], oacc[nj], 0, 0, 0);
    }
  };

  {
    bf16x8 kA[2][4], kB[2][4];
    LDK(0, kA);
#pragma unroll 1
    for (int tt = 0; tt < 8; ++tt) {
      LDK(2 * tt + 1, kB);
      P2(2 * tt, kA);
      if (tt < 7) LDK(2 * tt + 2, kA);
      P2(2 * tt + 1, kB);
    }
  }

  // ---- cross-wn O reduction through LDS, then bf16 store ----
  __syncthreads();
  float* osc = p_f32;  // [2][16][64]
  if (wn == 0) {
#pragma unroll
    for (int nj = 0; nj < 4; ++nj)
#pragma unroll
      for (int r = 0; r < 4; ++r)
        osc[(wm * 16 + lq * 4 + r) * 64 + nj * 16 + lrow] = oacc[nj][r];
  }
  __syncthreads();
  if (wn == 1) {
#pragma unroll
    for (int nj = 0; nj < 4; ++nj)
#pragma unroll
      for (int r = 0; r < 4; ++r) {
        int rr = m0 + wm * 16 + lq * 4 + r;
        float v = oacc[nj][r] + osc[(wm * 16 + lq * 4 + r) * 64 + nj * 16 + lrow];
        o[(size_t)(b * 2048 + rr) * 512 + h * 64 + nj * 16 + lrow] = f2bf(v);
      }
  }
}

extern "C" void kernel_launch(void* const* d_in, const int* in_sizes, int n_in,
                              void* d_out, int out_size, void* d_ws, size_t ws_size,
                              hipStream_t stream) {
  (void)in_sizes; (void)n_in; (void)out_size; (void)ws_size;
  const float* x        = (const float*)d_in[0];
  const float* ln1_w    = (const float*)d_in[1];
  const float* ln1_b    = (const float*)d_in[2];
  const float* qkv_w    = (const float*)d_in[3];
  const float* qkv_b    = (const float*)d_in[4];
  const float* out_w    = (const float*)d_in[5];
  const float* out_b    = (const float*)d_in[6];
  const float* rel_bias = (const float*)d_in[7];
  const float* gamma1   = (const float*)d_in[8];
  const float* ln2_w    = (const float*)d_in[9];
  const float* ln2_b    = (const float*)d_in[10];
  const float* ffn_in_w = (const float*)d_in[11];
  const float* ffn_in_b = (const float*)d_in[12];
  const float* ffn_out_w  = (const float*)d_in[13];
  const float* ffn_out_b  = (const float*)d_in[14];
  const float* gamma2   = (const float*)d_in[15];

  float* x_out = (float*)d_out;                       // (2,2048,512)
  float* attn  = x_out + (size_t)2 * 2048 * 512;      // (2,8,2048,2048)

  // workspace layout
  float* ws  = (float*)d_ws;
  float* x1  = ws;                                          // 4096x512 fp32
  unsigned short* h_bf  = (unsigned short*)(x1 + 2097152);  // 4096x512 bf16
  unsigned short* o_bf  = h_bf + 2097152;                   // 4096x512 bf16
  unsigned short* f_bf  = o_bf + 2097152;                   // 4096x2048 bf16 (FFN1 out)
  unsigned short* qkvbf = f_bf;                             // 4096x1536 bf16 (alias, pre-FFN1)
  unsigned short* bt_qkv  = f_bf + 8388608;                 // 1536x512
  unsigned short* bt_out  = bt_qkv + 786432;                // 512x512
  unsigned short* bt_ffn1 = bt_out + 262144;                // 4096x512
  unsigned short* bt_ffn2 = bt_ffn1 + 2097152;              // 512x2048
  unsigned short* vt      = bt_ffn2 + 1048576;              // 16 x 64 x 2048

  // all weight transposes in one launch
  transpose_all<<<4096, 256, 0, stream>>>(qkv_w, bt_qkv, out_w, bt_out,
                                          ffn_in_w, bt_ffn1, ffn_out_w, bt_ffn2);

  // LN1: x -> h_bf
  ln_kernel<<<4096, 256, 0, stream>>>(x, ln1_w, ln1_b, h_bf);

  // QKV GEMM: bf16 Q/K (scaled Q) -> qkvbf, V transposed bf16 -> vt
  gemm_bb<2, 2, 4, 2, 4><<<dim3(24, 32, 1), 256, 0, stream>>>(
      h_bf, bt_qkv, nullptr, qkvbf, vt, 512, 512, 512, 1536, qkv_b, nullptr, nullptr);

  // fused attention: softmax(QK^T*scale + rel) -> attn (d_out), O=PV -> o_bf
  attn_fused<<<dim3(64, 16, 1), 256, 0, stream>>>(qkvbf, vt, rel_bias, attn, o_bf);

  // out proj + residual: x1 = x + (o @ out_w + out_b) * gamma1
  gemm_bb<2, 2, 2, 2, 3><<<dim3(8, 64, 1), 256, 0, stream>>>(
      o_bf, bt_out, x1, nullptr, nullptr, 512, 512, 512, 512, out_b, x, gamma1);

  // LN2: x1 -> h_bf
  ln_kernel<<<4096, 256, 0, stream>>>(x1, ln2_w, ln2_b, h_bf);

  // FFN1 + gate fused: f_bf = gelu(h@Wb+bb) * (h@Wa+ba)
  ffn1_gate_kernel<<<dim3(32, 32, 1), 256, 0, stream>>>(h_bf, bt_ffn1, f_bf, ffn_in_b);

  // FFN2 + residual: x_out = x1 + (f @ ffn_out_w + ffn_out_b) * gamma2
  gemm_bb<2, 2, 2, 2, 3><<<dim3(8, 64, 1), 256, 0, stream>>>(
      f_bf, bt_ffn2, x_out, nullptr, nullptr, 2048, 2048, 2048, 512, ffn_out_b, x1, gamma2);
}

// Round 8
// 536.183 us; speedup vs baseline: 1.1039x; 1.1039x over previous
//
#include <hip/hip_runtime.h>
#include <math.h>

typedef __attribute__((ext_vector_type(4))) float f32x4;
typedef __attribute__((ext_vector_type(8))) short bf16x8;
typedef __attribute__((ext_vector_type(4))) short s16x4;

#if __has_builtin(__builtin_amdgcn_exp2f)
#define EXP2(x) __builtin_amdgcn_exp2f(x)
#else
#define EXP2(x) exp2f(x)
#endif

__device__ __forceinline__ unsigned short f2bf(float f) {
  union { float f; unsigned u; } v; v.f = f;
  return (unsigned short)((v.u + 0x7fffu + ((v.u >> 16) & 1u)) >> 16);
}

// ---------------- LayerNorm: one block per row of 512, bf16 output ----------------
__global__ void ln_kernel(const float* __restrict__ in, const float* __restrict__ w,
                          const float* __restrict__ b, unsigned short* __restrict__ out) {
  __shared__ float sh[4];
  const int t = threadIdx.x;
  const float* p = in + (size_t)blockIdx.x * 512;
  float a0 = p[t], a1 = p[t + 256];
  float s = a0 + a1;
#pragma unroll
  for (int o = 32; o; o >>= 1) s += __shfl_down(s, o);
  if ((t & 63) == 0) sh[t >> 6] = s;
  __syncthreads();
  s = sh[0] + sh[1] + sh[2] + sh[3];
  float mu = s * (1.0f / 512.0f);
  float d0 = a0 - mu, d1 = a1 - mu;
  float q = d0 * d0 + d1 * d1;
  __syncthreads();
#pragma unroll
  for (int o = 32; o; o >>= 1) q += __shfl_down(q, o);
  if ((t & 63) == 0) sh[t >> 6] = q;
  __syncthreads();
  q = sh[0] + sh[1] + sh[2] + sh[3];
  float rstd = rsqrtf(q * (1.0f / 512.0f) + 1e-5f);
  unsigned short* po = out + (size_t)blockIdx.x * 512;
  po[t]       = f2bf(d0 * rstd * w[t] + b[t]);
  po[t + 256] = f2bf(d1 * rstd * w[t + 256] + b[t + 256]);
}

// ---- ALL weight transposes in one launch: fp32 (K x N) -> bf16 (N x K) ----
__global__ void transpose_all(const float* __restrict__ w0, unsigned short* __restrict__ o0,
                              const float* __restrict__ w1, unsigned short* __restrict__ o1,
                              const float* __restrict__ w2, unsigned short* __restrict__ o2,
                              const float* __restrict__ w3, unsigned short* __restrict__ o3) {
  __shared__ float tile[32][33];
  int idx = blockIdx.x;
  const float* in; unsigned short* out; int ldi, ldo, nx;
  if (idx < 768)        { in = w0; out = o0; ldi = 1536; ldo = 512;  nx = 48; }
  else if (idx < 1024)  { idx -= 768;  in = w1; out = o1; ldi = 512;  ldo = 512;  nx = 16; }
  else if (idx < 3072)  { idx -= 1024; in = w2; out = o2; ldi = 4096; ldo = 512;  nx = 128; }
  else                  { idx -= 3072; in = w3; out = o3; ldi = 512;  ldo = 2048; nx = 16; }
  const int tx = threadIdx.x & 31;
  const int ty = threadIdx.x >> 5;  // 0..7
  const int n0 = (idx % nx) * 32, k0 = (idx / nx) * 32;
#pragma unroll
  for (int i = 0; i < 4; ++i)
    tile[ty + i * 8][tx] = in[(size_t)(k0 + ty + i * 8) * ldi + n0 + tx];
  __syncthreads();
#pragma unroll
  for (int i = 0; i < 4; ++i)
    out[(size_t)(n0 + ty + i * 8) * ldo + k0 + tx] = f2bf(tile[tx][ty + i * 8]);
}

// ---------------- bf16 x bf16 MFMA GEMM, BK=64, padded LDS ----------------
// EPI: 0 = +bias (fp32); 3 = resid + (acc+bias)*gamma (fp32);
//      4 = QKV: cols<1024 -> bf16 qkvbf (cols<512 pre-scaled by 0.125*log2e),
//               cols in [1024,1536) -> bf16 transposed into vt[bh][d][l]
template <int WM, int WN, int TM, int TN, int EPI>
__global__ __launch_bounds__(256) void gemm_bb(
    const unsigned short* __restrict__ A, const unsigned short* __restrict__ Bt,
    float* __restrict__ C, unsigned short* __restrict__ Cbf, unsigned short* __restrict__ Vt,
    int K, int lda, int ldb, int ldc,
    const float* __restrict__ bias, const float* __restrict__ resid,
    const float* __restrict__ gamma) {
  constexpr int BM = WM * TM * 16;
  constexpr int BN = WN * TN * 16;
  constexpr int LDS_STRIDE = 72;   // 64 + 8 pad: breaks 8-way bank conflicts
  __shared__ short As[BM * LDS_STRIDE];
  __shared__ short Bs[BN * LDS_STRIDE];

  const int tid = threadIdx.x;
  const int m0 = blockIdx.y * BM, n0 = blockIdx.x * BN;
  const int w = tid >> 6, lane = tid & 63;
  const int wm = w / WN, wn = w % WN;
  const int lrow = lane & 15, lq = lane >> 4;

  f32x4 acc[TM][TN];
#pragma unroll
  for (int i = 0; i < TM; ++i)
#pragma unroll
    for (int j = 0; j < TN; ++j) acc[i][j] = (f32x4){0.f, 0.f, 0.f, 0.f};

  for (int k0 = 0; k0 < K; k0 += 64) {
    __syncthreads();
#pragma unroll
    for (int it = 0; it < BM / 32; ++it) {
      int c = it * 256 + tid;
      int row = c >> 3, col = (c & 7) << 3;
      *(bf16x8*)(As + row * LDS_STRIDE + col) =
          *(const bf16x8*)(A + (size_t)(m0 + row) * lda + k0 + col);
    }
#pragma unroll
    for (int it = 0; it < BN / 32; ++it) {
      int c = it * 256 + tid;
      int row = c >> 3, col = (c & 7) << 3;
      *(bf16x8*)(Bs + row * LDS_STRIDE + col) =
          *(const bf16x8*)(Bt + (size_t)(n0 + row) * ldb + k0 + col);
    }
    __syncthreads();

    bf16x8 af[TM][2], bf[TN][2];
#pragma unroll
    for (int mi = 0; mi < TM; ++mi)
#pragma unroll
      for (int c = 0; c < 2; ++c)
        af[mi][c] = *(const bf16x8*)(As + (wm * TM * 16 + mi * 16 + lrow) * LDS_STRIDE + c * 32 + lq * 8);
#pragma unroll
    for (int nj = 0; nj < TN; ++nj)
#pragma unroll
      for (int c = 0; c < 2; ++c)
        bf[nj][c] = *(const bf16x8*)(Bs + (wn * TN * 16 + nj * 16 + lrow) * LDS_STRIDE + c * 32 + lq * 8);
#pragma unroll
    for (int mi = 0; mi < TM; ++mi)
#pragma unroll
      for (int nj = 0; nj < TN; ++nj)
#pragma unroll
        for (int c = 0; c < 2; ++c)
          acc[mi][nj] = __builtin_amdgcn_mfma_f32_16x16x32_bf16(af[mi][c], bf[nj][c], acc[mi][nj], 0, 0, 0);
  }

#pragma unroll
  for (int mi = 0; mi < TM; ++mi) {
#pragma unroll
    for (int nj = 0; nj < TN; ++nj) {
      int gm0 = m0 + wm * TM * 16 + mi * 16 + lq * 4;
      int gn = n0 + wn * TN * 16 + nj * 16 + lrow;
      if constexpr (EPI == 4) {
        if (gn >= 1024) {
          // V columns -> vt[bh][d][l] transposed bf16 (4 consecutive l per thread)
          int h = (gn - 1024) >> 6, dd = (gn - 1024) & 63;
          int bb = gm0 >> 11, l0 = gm0 & 2047;
          float bs = bias[gn];
          s16x4 r4 = {(short)f2bf(acc[mi][nj][0] + bs), (short)f2bf(acc[mi][nj][1] + bs),
                      (short)f2bf(acc[mi][nj][2] + bs), (short)f2bf(acc[mi][nj][3] + bs)};
          *(s16x4*)(Vt + ((size_t)(bb * 8 + h) * 64 + dd) * 2048 + l0) = r4;
          continue;
        }
      }
#pragma unroll
      for (int r = 0; r < 4; ++r) {
        int gm = gm0 + r;
        size_t idx = (size_t)gm * ldc + gn;
        float v = acc[mi][nj][r];
        if constexpr (EPI == 0) {
          C[idx] = v + bias[gn];
        } else if constexpr (EPI == 4) {
          float u = v + bias[gn];
          Cbf[idx] = f2bf(gn < 512 ? u * 0.18033688011112042f : u);
        } else {
          C[idx] = resid[idx] + (v + bias[gn]) * gamma[gn];
        }
      }
    }
  }
}

// --------- FFN1 + GELU gate fused, BK=64, padded LDS, bf16 out ---------
__global__ __launch_bounds__(256) void ffn1_gate_kernel(
    const unsigned short* __restrict__ A, const unsigned short* __restrict__ Bt,
    unsigned short* __restrict__ F, const float* __restrict__ bias) {
  constexpr int LDS_STRIDE = 72;
  __shared__ short As[128 * LDS_STRIDE];
  __shared__ short Bs[64 * LDS_STRIDE];
  __shared__ short Bs2[64 * LDS_STRIDE];

  const int tid = threadIdx.x;
  const int n0 = blockIdx.x * 64, m0 = blockIdx.y * 128;
  const int w = tid >> 6, lane = tid & 63;
  const int wm = w >> 1, wn = w & 1;
  const int lrow = lane & 15, lq = lane >> 4;

  f32x4 acca[4][2], accb[4][2];
#pragma unroll
  for (int i = 0; i < 4; ++i)
#pragma unroll
    for (int j = 0; j < 2; ++j) {
      acca[i][j] = (f32x4){0.f, 0.f, 0.f, 0.f};
      accb[i][j] = (f32x4){0.f, 0.f, 0.f, 0.f};
    }

  for (int k0 = 0; k0 < 512; k0 += 64) {
    __syncthreads();
#pragma unroll
    for (int it = 0; it < 4; ++it) {
      int c = it * 256 + tid;
      int row = c >> 3, col = (c & 7) << 3;
      *(bf16x8*)(As + row * LDS_STRIDE + col) =
          *(const bf16x8*)(A + (size_t)(m0 + row) * 512 + k0 + col);
    }
#pragma unroll
    for (int it = 0; it < 2; ++it) {
      int c = it * 256 + tid;
      int row = c >> 3, col = (c & 7) << 3;
      *(bf16x8*)(Bs + row * LDS_STRIDE + col) =
          *(const bf16x8*)(Bt + (size_t)(n0 + row) * 512 + k0 + col);
      *(bf16x8*)(Bs2 + row * LDS_STRIDE + col) =
          *(const bf16x8*)(Bt + (size_t)(2048 + n0 + row) * 512 + k0 + col);
    }
    __syncthreads();

    bf16x8 af[4][2], ba[2][2], bb[2][2];
#pragma unroll
    for (int mi = 0; mi < 4; ++mi)
#pragma unroll
      for (int c = 0; c < 2; ++c)
        af[mi][c] = *(const bf16x8*)(As + (wm * 64 + mi * 16 + lrow) * LDS_STRIDE + c * 32 + lq * 8);
#pragma unroll
    for (int nj = 0; nj < 2; ++nj)
#pragma unroll
      for (int c = 0; c < 2; ++c) {
        ba[nj][c] = *(const bf16x8*)(Bs + (wn * 32 + nj * 16 + lrow) * LDS_STRIDE + c * 32 + lq * 8);
        bb[nj][c] = *(const bf16x8*)(Bs2 + (wn * 32 + nj * 16 + lrow) * LDS_STRIDE + c * 32 + lq * 8);
      }
#pragma unroll
    for (int mi = 0; mi < 4; ++mi)
#pragma unroll
      for (int nj = 0; nj < 2; ++nj)
#pragma unroll
        for (int c = 0; c < 2; ++c) {
          acca[mi][nj] = __builtin_amdgcn_mfma_f32_16x16x32_bf16(af[mi][c], ba[nj][c], acca[mi][nj], 0, 0, 0);
          accb[mi][nj] = __builtin_amdgcn_mfma_f32_16x16x32_bf16(af[mi][c], bb[nj][c], accb[mi][nj], 0, 0, 0);
        }
  }

#pragma unroll
  for (int mi = 0; mi < 4; ++mi)
#pragma unroll
    for (int nj = 0; nj < 2; ++nj) {
      int gm0 = m0 + wm * 64 + mi * 16 + lq * 4;
      int gn = n0 + wn * 32 + nj * 16 + lrow;
#pragma unroll
      for (int r = 0; r < 4; ++r) {
        float a = acca[mi][nj][r] + bias[gn];
        float bg = accb[mi][nj][r] + bias[2048 + gn];
        float g = 0.5f * bg * (1.0f + erff(bg * 0.70710678118654752f));
        F[(size_t)(gm0 + r) * 2048 + gn] = f2bf(g * a);
      }
    }
}

// --------- Fused attention (R5-proven): coalesced attn stores via swizzled LDS staging ---------
// Block: 32 q-rows x one (b,h). 4 waves: wm (2) splits rows, wn (2) splits keys.
__global__ __launch_bounds__(256, 4) void attn_fused(
    const unsigned short* __restrict__ qkvbf, const unsigned short* __restrict__ vt,
    const float* __restrict__ rel, float* __restrict__ attn, unsigned short* __restrict__ o) {
  __shared__ __align__(16) float p_f32[4 * 16 * 64];  // 16 KB wave-private staging; reused as O scratch
  __shared__ float erel[256];
  __shared__ float rsum[32];
  __shared__ float rinv[32];

  const int tid = threadIdx.x;
  const int flat = blockIdx.y * 64 + blockIdx.x;   // 1024 blocks
  const int swz = (flat & 7) * 128 + (flat >> 3);  // XCD-contiguous
  const int bh = swz >> 6;
  const int m0 = (swz & 63) * 32;
  const int b = bh >> 3, h = bh & 7;

  const int w = tid >> 6, lane = tid & 63;
  const int wm = w >> 1, wn = w & 1;
  const int lrow = lane & 15, lq = lane >> 4;

  const unsigned short* qb = qkvbf + (size_t)(b * 2048) * 1536 + h * 64;
  const unsigned short* kb = qb + 512;
  const unsigned short* vb = vt + (size_t)bh * 64 * 2048;
  float* ab = attn + (size_t)bh * 2048 * 2048;
  const float* relh = rel + h * 255;

  if (tid < 32) rsum[tid] = 0.f;
  if (tid < 255) erel[tid] = __expf(relh[tid]);

  bf16x8 qf[2];
#pragma unroll
  for (int c = 0; c < 2; ++c)
    qf[c] = *(const bf16x8*)(qb + (size_t)(m0 + wm * 16 + lrow) * 1536 + c * 32 + lq * 8);

  const unsigned short* krow = kb + (size_t)(wn * 64 + lrow) * 1536 + lq * 8;
  const unsigned short* vrow = vb + (size_t)lrow * 2048 + wn * 64 + lq * 8;

  __syncthreads();  // erel + rsum ready

  // ---- pass 1: row sums of exp(s) ----
  float psum[4] = {0.f, 0.f, 0.f, 0.f};
  const int dbase = (m0 + wm * 16 + lq * 4) - (wn * 64 + lrow);
  for (int t = 0; t < 16; ++t) {
    const int kt0 = t * 128;
    f32x4 acc[4];
#pragma unroll
    for (int nj = 0; nj < 4; ++nj) acc[nj] = (f32x4){0.f, 0.f, 0.f, 0.f};
#pragma unroll
    for (int c = 0; c < 2; ++c) {
      bf16x8 kf[4];
#pragma unroll
      for (int nj = 0; nj < 4; ++nj)
        kf[nj] = *(const bf16x8*)(krow + (size_t)(kt0 + nj * 16) * 1536 + c * 32);
#pragma unroll
      for (int nj = 0; nj < 4; ++nj)
        acc[nj] = __builtin_amdgcn_mfma_f32_16x16x32_bf16(qf[c], kf[nj], acc[nj], 0, 0, 0);
    }
    const int Dt = m0 - kt0;
    if (Dt >= 256 || Dt <= -160) {      // fully clamped tile: uniform rel bias
      float ec = erel[Dt >= 256 ? 254 : 0];
#pragma unroll
      for (int r = 0; r < 4; ++r) {
        float s = 0.f;
#pragma unroll
        for (int nj = 0; nj < 4; ++nj) s += EXP2(acc[nj][r]);
        psum[r] += ec * s;
      }
    } else {
#pragma unroll
      for (int nj = 0; nj < 4; ++nj) {
        int d0 = dbase - kt0 - nj * 16;
#pragma unroll
        for (int r = 0; r < 4; ++r) {
          int d = d0 + r;
          d = d < -127 ? -127 : (d > 127 ? 127 : d);
          psum[r] += EXP2(acc[nj][r]) * erel[d + 127];
        }
      }
    }
  }
#pragma unroll
  for (int off = 1; off < 16; off <<= 1)
#pragma unroll
    for (int r = 0; r < 4; ++r) psum[r] += __shfl_xor(psum[r], off);
  if (lrow == 0) {
#pragma unroll
    for (int r = 0; r < 4; ++r) atomicAdd(&rsum[wm * 16 + lq * 4 + r], psum[r]);
  }
  __syncthreads();
  if (tid < 32) rinv[tid] = 1.0f / rsum[tid];
  __syncthreads();
  float rv[4];
#pragma unroll
  for (int r = 0; r < 4; ++r) rv[r] = rinv[wm * 16 + lq * 4 + r];

  // ---- pass 2: recompute S, stage in LDS, coalesced attn store, O += P @ V ----
  f32x4 oacc[4];
#pragma unroll
  for (int nj = 0; nj < 4; ++nj) oacc[nj] = (f32x4){0.f, 0.f, 0.f, 0.f};
  float* pw = p_f32 + w * (16 * 64);   // wave-private 4 KB

  const int wsw = lq << 4;
  const int rsw = ((lrow >> 2) & 3) << 4;

  for (int t = 0; t < 16; ++t) {
    const int kt0 = t * 128;
    f32x4 acc[4];
#pragma unroll
    for (int nj = 0; nj < 4; ++nj) acc[nj] = (f32x4){0.f, 0.f, 0.f, 0.f};
#pragma unroll
    for (int c = 0; c < 2; ++c) {
      bf16x8 kf[4];
#pragma unroll
      for (int nj = 0; nj < 4; ++nj)
        kf[nj] = *(const bf16x8*)(krow + (size_t)(kt0 + nj * 16) * 1536 + c * 32);
#pragma unroll
      for (int nj = 0; nj < 4; ++nj)
        acc[nj] = __builtin_amdgcn_mfma_f32_16x16x32_bf16(qf[c], kf[nj], acc[nj], 0, 0, 0);
    }

    const int Dt = m0 - kt0;
    if (Dt >= 256 || Dt <= -160) {
      float ec = erel[Dt >= 256 ? 254 : 0];
#pragma unroll
      for (int r = 0; r < 4; ++r) {
        float fr = ec * rv[r];
        int prow = lq * 4 + r;
#pragma unroll
        for (int nj = 0; nj < 4; ++nj) {
          float e = EXP2(acc[nj][r]) * fr;
          pw[prow * 64 + ((nj * 16 + lrow) ^ wsw)] = e;
        }
      }
    } else {
#pragma unroll
      for (int r = 0; r < 4; ++r) {
        int prow = lq * 4 + r;
        int d0 = dbase - kt0 + r;
#pragma unroll
        for (int nj = 0; nj < 4; ++nj) {
          int d = d0 - nj * 16;
          d = d < -127 ? -127 : (d > 127 ? 127 : d);
          float e = EXP2(acc[nj][r]) * (erel[d + 127] * rv[r]);
          pw[prow * 64 + ((nj * 16 + lrow) ^ wsw)] = e;
        }
      }
    }

#pragma unroll
    for (int it = 0; it < 4; ++it) {
      int rr = lq * 4 + it;
      f32x4 vv = *(const f32x4*)(pw + rr * 64 + ((lrow * 4) ^ wsw));
      __builtin_nontemporal_store(
          vv, (f32x4*)(ab + (size_t)(m0 + wm * 16 + rr) * 2048 + kt0 + wn * 64 + lrow * 4));
    }

#pragma unroll
    for (int c2 = 0; c2 < 2; ++c2) {
      const float* pp = pw + lrow * 64 + ((c2 * 32 + lq * 8) ^ rsw);
      f32x4 pa = *(const f32x4*)pp;
      f32x4 pb = *(const f32x4*)(pp + 4);
      bf16x8 ap = {(short)f2bf(pa[0]), (short)f2bf(pa[1]), (short)f2bf(pa[2]), (short)f2bf(pa[3]),
                   (short)f2bf(pb[0]), (short)f2bf(pb[1]), (short)f2bf(pb[2]), (short)f2bf(pb[3])};
      bf16x8 bv[4];
#pragma unroll
      for (int nj = 0; nj < 4; ++nj)
        bv[nj] = *(const bf16x8*)(vrow + (size_t)(nj * 16) * 2048 + kt0 + c2 * 32);
#pragma unroll
      for (int nj = 0; nj < 4; ++nj)
        oacc[nj] = __builtin_amdgcn_mfma_f32_16x16x32_bf16(ap, bv[nj], oacc[nj], 0, 0, 0);
    }
  }

  // ---- cross-wn O reduction through LDS, then bf16 store ----
  __syncthreads();
  float* osc = p_f32;  // [2][16][64]
  if (wn == 0) {
#pragma unroll
    for (int nj = 0; nj < 4; ++nj)
#pragma unroll
      for (int r = 0; r < 4; ++r)
        osc[(wm * 16 + lq * 4 + r) * 64 + nj * 16 + lrow] = oacc[nj][r];
  }
  __syncthreads();
  if (wn == 1) {
#pragma unroll
    for (int nj = 0; nj < 4; ++nj)
#pragma unroll
      for (int r = 0; r < 4; ++r) {
        int rr = m0 + wm * 16 + lq * 4 + r;
        float v = oacc[nj][r] + osc[(wm * 16 + lq * 4 + r) * 64 + nj * 16 + lrow];
        o[(size_t)(b * 2048 + rr) * 512 + h * 64 + nj * 16 + lrow] = f2bf(v);
      }
  }
}

extern "C" void kernel_launch(void* const* d_in, const int* in_sizes, int n_in,
                              void* d_out, int out_size, void* d_ws, size_t ws_size,
                              hipStream_t stream) {
  (void)in_sizes; (void)n_in; (void)out_size; (void)ws_size;
  const float* x        = (const float*)d_in[0];
  const float* ln1_w    = (const float*)d_in[1];
  const float* ln1_b    = (const float*)d_in[2];
  const float* qkv_w    = (const float*)d_in[3];
  const float* qkv_b    = (const float*)d_in[4];
  const float* out_w    = (const float*)d_in[5];
  const float* out_b    = (const float*)d_in[6];
  const float* rel_bias = (const float*)d_in[7];
  const float* gamma1   = (const float*)d_in[8];
  const float* ln2_w    = (const float*)d_in[9];
  const float* ln2_b    = (const float*)d_in[10];
  const float* ffn_in_w = (const float*)d_in[11];
  const float* ffn_in_b = (const float*)d_in[12];
  const float* ffn_out_w  = (const float*)d_in[13];
  const float* ffn_out_b  = (const float*)d_in[14];
  const float* gamma2   = (const float*)d_in[15];

  float* x_out = (float*)d_out;                       // (2,2048,512)
  float* attn  = x_out + (size_t)2 * 2048 * 512;      // (2,8,2048,2048)

  // workspace layout
  float* ws  = (float*)d_ws;
  float* x1  = ws;                                          // 4096x512 fp32
  unsigned short* h_bf  = (unsigned short*)(x1 + 2097152);  // 4096x512 bf16
  unsigned short* o_bf  = h_bf + 2097152;                   // 4096x512 bf16
  unsigned short* f_bf  = o_bf + 2097152;                   // 4096x2048 bf16 (FFN1 out)
  unsigned short* qkvbf = f_bf;                             // 4096x1536 bf16 (alias, pre-FFN1)
  unsigned short* bt_qkv  = f_bf + 8388608;                 // 1536x512
  unsigned short* bt_out  = bt_qkv + 786432;                // 512x512
  unsigned short* bt_ffn1 = bt_out + 262144;                // 4096x512
  unsigned short* bt_ffn2 = bt_ffn1 + 2097152;              // 512x2048
  unsigned short* vt      = bt_ffn2 + 1048576;              // 16 x 64 x 2048

  // all weight transposes in one launch
  transpose_all<<<4096, 256, 0, stream>>>(qkv_w, bt_qkv, out_w, bt_out,
                                          ffn_in_w, bt_ffn1, ffn_out_w, bt_ffn2);

  // LN1: x -> h_bf
  ln_kernel<<<4096, 256, 0, stream>>>(x, ln1_w, ln1_b, h_bf);

  // QKV GEMM: bf16 Q/K (scaled Q) -> qkvbf, V transposed bf16 -> vt
  gemm_bb<2, 2, 4, 2, 4><<<dim3(24, 32, 1), 256, 0, stream>>>(
      h_bf, bt_qkv, nullptr, qkvbf, vt, 512, 512, 512, 1536, qkv_b, nullptr, nullptr);

  // fused attention: softmax(QK^T*scale + rel) -> attn (d_out), O=PV -> o_bf
  attn_fused<<<dim3(64, 16, 1), 256, 0, stream>>>(qkvbf, vt, rel_bias, attn, o_bf);

  // out proj + residual: x1 = x + (o @ out_w + out_b) * gamma1
  gemm_bb<2, 2, 2, 2, 3><<<dim3(8, 64, 1), 256, 0, stream>>>(
      o_bf, bt_out, x1, nullptr, nullptr, 512, 512, 512, 512, out_b, x, gamma1);

  // LN2: x1 -> h_bf
  ln_kernel<<<4096, 256, 0, stream>>>(x1, ln2_w, ln2_b, h_bf);

  // FFN1 + gate fused: f_bf = gelu(h@Wb+bb) * (h@Wa+ba)
  ffn1_gate_kernel<<<dim3(32, 32, 1), 256, 0, stream>>>(h_bf, bt_ffn1, f_bf, ffn_in_b);

  // FFN2 + residual: x_out = x1 + (f @ ffn_out_w + ffn_out_b) * gamma2
  gemm_bb<2, 2, 2, 2, 3><<<dim3(8, 64, 1), 256, 0, stream>>>(
      f_bf, bt_ffn2, x_out, nullptr, nullptr, 2048, 2048, 2048, 512, ffn_out_b, x1, gamma2);
}